// Round 4
// baseline (152.330 us; speedup 1.0000x reference)
//
#include <hip/hip_runtime.h>

#define BB 4
#define NN 4096
#define DD 64
#define KK 16

// ws float offsets
#define OFF_EMB   0u          // B*N*D = 1048576 (fp32 normalized emb)
#define OFF_NRM2  1310720u    // B*N   = 16384
#define OFF_FCSUM 1327104u    // B*K*D = 4096
#define OFF_GCSUM 1331200u    // B*K*3 = 192
#define OFF_CNT   1331392u    // B*K   = 64
#define OFF_FC    1331456u    // 4096
#define OFF_GC    1339648u    // 192
#define OFF_FCN2  1339840u    // 64
#define OFF_FCN   1339904u    // 64
#define OFF_CEN2  1339968u    // 64
#define OFF_GC2   1340032u    // 64
#define OFF_ACC   1340096u    // 8 doubles (16 floats), 8B aligned
#define OFF_EMBH  1340112u    // bf16 normalized emb
// acc: 0 var, 1 dist, 2 reg, 3 center, 4 boundary(raw upper-pair sum), 5 lovasz

typedef __attribute__((ext_vector_type(8))) short bf16x8;
typedef __attribute__((ext_vector_type(4))) float f32x4;
typedef unsigned long long ull;

__device__ __forceinline__ ushort f2bf(float x){
  unsigned u = __float_as_uint(x);
  return (ushort)((u + 0x7FFFu + ((u >> 16) & 1u)) >> 16);
}

__device__ __forceinline__ float blockReduceSum(float v, float* sbuf){
  int t = threadIdx.x;
  #pragma unroll
  for (int off = 32; off > 0; off >>= 1) v += __shfl_xor(v, off, 64);
  if ((t & 63) == 0) sbuf[t >> 6] = v;
  __syncthreads();
  float s = 0.f;
  if (t == 0){
    int nw = blockDim.x >> 6;
    for (int i = 0; i < nw; i++) s += sbuf[i];
  }
  __syncthreads();
  return s;
}

// Normalize embeddings, per-instance sums. One wave handles 8 points; lane = dim.
__global__ void knormacc(const float* __restrict__ emb, const float* __restrict__ pts,
                         const int* __restrict__ lbl, float* __restrict__ ws){
  __shared__ float fcl[KK * DD];
  __shared__ float gcl[KK * 3];
  __shared__ float cntl[KK];
  int t = threadIdx.x;
  if (blockIdx.x == 0 && t < 16) ws[OFF_ACC + t] = 0.f;
  for (int i = t; i < KK * DD; i += 256) fcl[i] = 0.f;
  if (t < KK * 3) gcl[t] = 0.f;
  if (t < KK) cntl[t] = 0.f;
  __syncthreads();

  int lane = t & 63, w = t >> 6;
  int b = blockIdx.x >> 7;
  int local = blockIdx.x & 127;
  int base = local * 32 + w * 8;
  const float* E = emb + (size_t)b * NN * DD;
  float* EN = ws + OFF_EMB + (size_t)b * NN * DD;
  ushort* EH = (ushort*)(ws + OFF_EMBH) + (size_t)b * NN * DD;

  for (int i = 0; i < 8; i++){
    int n = base + i;
    float v = E[(size_t)n * DD + lane];
    float ss = v * v;
    #pragma unroll
    for (int off = 1; off < 64; off <<= 1) ss += __shfl_xor(ss, off, 64);
    float nrm = sqrtf(ss);
    float scale = 1.0f / fmaxf(nrm, 1e-12f);
    float vn = v * scale;
    EN[(size_t)n * DD + lane] = vn;
    EH[(size_t)n * DD + lane] = f2bf(vn);
    if (lane == 0) ws[OFF_NRM2 + b * NN + n] = ss * scale * scale;
    int l = lbl[b * NN + n];
    if (l >= 1 && l <= KK){
      int k = l - 1;
      atomicAdd(&fcl[k * DD + lane], vn);
      if (lane < 3) atomicAdd(&gcl[k * 3 + lane], pts[((size_t)b * NN + n) * 3 + lane]);
      if (lane == 0) atomicAdd(&cntl[k], 1.0f);
    }
  }
  __syncthreads();
  for (int i = t; i < KK * DD; i += 256) atomicAdd(&ws[OFF_FCSUM + b * KK * DD + i], fcl[i]);
  if (t < KK * 3) atomicAdd(&ws[OFF_GCSUM + b * KK * 3 + t], gcl[t]);
  if (t < KK)     atomicAdd(&ws[OFF_CNT + b * KK + t], cntl[t]);
}

// Finalize centers, dist loss, reg loss. One block per batch; lane = dim, wave = k-group.
__global__ void kcenters(float* __restrict__ ws, double* __restrict__ acc){
  __shared__ float cenS[KK][DD];
  __shared__ float cen2S[KK];
  __shared__ float red[16];
  int b = blockIdx.x, t = threadIdx.x;
  int lane = t & 63, w = t >> 6;
  for (int k = w; k < KK; k += 4){
    float c = ws[OFF_CNT + b * KK + k];
    float inv_c = 1.f / c;
    float f = ws[OFF_FCSUM + (b * KK + k) * DD + lane] * inv_c;
    ws[OFF_FC + (b * KK + k) * DD + lane] = f;
    float n2 = f * f;
    #pragma unroll
    for (int off = 1; off < 64; off <<= 1) n2 += __shfl_xor(n2, off, 64);
    float fn = sqrtf(n2);
    float inv = 1.f / fmaxf(fn, 1e-12f);
    float ce = f * inv;
    cenS[k][lane] = ce;
    float c2 = ce * ce;
    #pragma unroll
    for (int off = 1; off < 64; off <<= 1) c2 += __shfl_xor(c2, off, 64);
    float g = (lane < 3) ? ws[OFF_GCSUM + (b * KK + k) * 3 + lane] * inv_c : 0.f;
    if (lane < 3) ws[OFF_GC + (b * KK + k) * 3 + lane] = g;
    float g2 = g * g;
    g2 += __shfl_xor(g2, 1, 64);
    g2 += __shfl_xor(g2, 2, 64);
    if (lane == 0){
      ws[OFF_FCN2 + b * KK + k] = n2;
      ws[OFF_FCN + b * KK + k] = fn;
      ws[OFF_CEN2 + b * KK + k] = c2;
      ws[OFF_GC2 + b * KK + k] = g2;
      cen2S[k] = c2;
    }
  }
  __syncthreads();
  int i = t >> 4, j = t & 15;
  float v = 0.f;
  if (i != j){
    float dot = 0.f;
    #pragma unroll
    for (int d = 0; d < DD; d++) dot += cenS[i][d] * cenS[j][d];
    float cd = sqrtf(fmaxf(cen2S[i] + cen2S[j] - 2.f * dot, 0.f));
    v = fmaxf(3.f - cd, 0.f);
  }
  float s = blockReduceSum(v, red);
  if (t == 0){
    atomicAdd(&acc[1], (double)(s / 240.f));
    float s2 = 0.f;
    for (int k = 0; k < KK; k++) s2 += cen2S[k];
    atomicAdd(&acc[2], (double)(sqrtf(s2) * 0.001f));
  }
}

// Per-point var/center losses (own label only). 64 blocks x 256.
__global__ void kperpoint(const float* __restrict__ pts, const int* __restrict__ lbl,
                          float* __restrict__ ws, double* __restrict__ acc){
  __shared__ float4 fcl4[KK][16];
  __shared__ float fcn2S[KK], cen2S[KK], cntS[KK], invS[KK], gc2S[KK];
  __shared__ float gcS[KK][3];
  __shared__ float red[16];
  int t = threadIdx.x;
  int g = blockIdx.x * 256 + t;
  int b = g >> 12;
  int n = g & (NN - 1);
  for (int i = t; i < KK * DD / 4; i += 256) ((float4*)fcl4)[i] = ((const float4*)(ws + OFF_FC + b * KK * DD))[i];
  if (t < KK){
    float fn = ws[OFF_FCN + b * KK + t];
    fcn2S[t] = ws[OFF_FCN2 + b * KK + t];
    cen2S[t] = ws[OFF_CEN2 + b * KK + t];
    cntS[t] = ws[OFF_CNT + b * KK + t];
    invS[t] = 1.f / fmaxf(fn, 1e-12f);
    gc2S[t] = ws[OFF_GC2 + b * KK + t];
    gcS[t][0] = ws[OFF_GC + (b * KK + t) * 3 + 0];
    gcS[t][1] = ws[OFF_GC + (b * KK + t) * 3 + 1];
    gcS[t][2] = ws[OFF_GC + (b * KK + t) * 3 + 2];
  }
  __syncthreads();

  int l = lbl[b * NN + n];
  float varA = 0.f, cenA = 0.f;
  if (l >= 1 && l <= KK){
    int k = l - 1;
    const float* EN = ws + OFF_EMB + ((size_t)(b * NN + n)) * DD;
    float dot = 0.f;
    #pragma unroll
    for (int i = 0; i < 16; i++){
      float4 e = *(const float4*)&EN[i * 4];
      float4 f = fcl4[k][i];
      dot += e.x * f.x + e.y * f.y + e.z * f.z + e.w * f.w;
    }
    float nrm2 = ws[OFF_NRM2 + b * NN + n];
    float p0 = pts[((size_t)b * NN + n) * 3 + 0];
    float p1 = pts[((size_t)b * NN + n) * 3 + 1];
    float p2 = pts[((size_t)b * NN + n) * 3 + 2];
    float p2sum = p0 * p0 + p1 * p1 + p2 * p2;
    float dotc = dot * invS[k];
    float dnc = sqrtf(fmaxf(nrm2 + cen2S[k] - 2.f * dotc, 0.f));
    varA = fmaxf(dnc - 0.5f, 0.f) / cntS[k];
    float fd = sqrtf(fmaxf(nrm2 + fcn2S[k] - 2.f * dot, 0.f));
    float gd2 = p2sum + gc2S[k] - 2.f * (p0 * gcS[k][0] + p1 * gcS[k][1] + p2 * gcS[k][2]);
    float sd = sqrtf(fmaxf(gd2, 0.f));
    cenA = sd * fd / cntS[k];
  }
  float vs = blockReduceSum(varA, red);
  if (t == 0) atomicAdd(&acc[0], (double)vs);
  float cs = blockReduceSum(cenA, red);
  if (t == 0) atomicAdd(&acc[3], (double)cs);
}

// Fused: blocks 0..63 = lovasz (one per (b,k)); blocks 64.. = boundary 128x128 tiles.
__global__ __launch_bounds__(256, 4) void kfused(const int* __restrict__ lbl,
                                                 const ushort* __restrict__ EHg,
                                                 float* __restrict__ ws,
                                                 double* __restrict__ accd){
  __shared__ union SMem {
    struct { ull buf[2048]; float red[16]; int wt[4]; } lv;   // 16.2 KB
    struct { float red[16]; } bd;
  } sm;
  int t = threadIdx.x;

  if (blockIdx.x < 64){
    // ================= LOVASZ =================
    int bk = blockIdx.x;
    int b = bk >> 4, k = bk & 15;
    int lane = t & 63;
    int w = t >> 6;
    int q = t & 3;        // dim quarter
    int qd = t >> 2;      // quad: owns 64 consecutive points
    const float* EN = ws + OFF_EMB + (size_t)b * NN * DD;
    const float* NR = ws + OFF_NRM2 + b * NN;

    float4 fq[4];
    #pragma unroll
    for (int i = 0; i < 4; i++)
      fq[i] = *(const float4*)&ws[OFF_FC + (b * KK + k) * DD + q * 16 + i * 4];
    float mfn = fmaxf(ws[OFF_FCN + b * KK + k], 1e-8f);

    // --- sims in-register: quad cooperates on each point's 64-dim dot ---
    ull key[16];
    for (int c = 0; c < 4; c++){
      #pragma unroll
      for (int s = 0; s < 16; s++){
        int p = qd * 64 + c * 16 + s;
        const float* ep = &EN[(size_t)p * DD + q * 16];
        float dot = 0.f;
        #pragma unroll
        for (int i = 0; i < 4; i++){
          float4 e = *(const float4*)&ep[i * 4];
          dot += e.x * fq[i].x + e.y * fq[i].y + e.z * fq[i].z + e.w * fq[i].w;
        }
        dot += __shfl_xor(dot, 1, 64);
        dot += __shfl_xor(dot, 2, 64);
        if (q == c){
          float nn = NR[p];
          float sim = dot / (fmaxf(sqrtf(nn), 1e-8f) * mfn);
          unsigned u = __float_as_uint(sim);
          unsigned a = (u & 0x80000000u) ? ~u : (u | 0x80000000u);
          key[s] = ((ull)(~a) << 32) | (unsigned)p;
        }
      }
    }

    // --- bitonic sort, p = t*16+s ownership ---
    for (int k2 = 1; k2 <= 12; k2++){
      const int S = 1 << k2;
      for (int j = k2 - 1; j >= 0; j--){
        const int sig = 1 << j;
        if (j >= 10){
          // cross-wave via LDS, 8-slot halves
          int tm = sig >> 4;   // 64 or 128
          bool up = (((t << 4) & S) == 0);
          bool low = ((t & tm) == 0);
          #pragma unroll
          for (int half = 0; half < 2; half++){
            __syncthreads();
            #pragma unroll
            for (int s = 0; s < 8; s++) sm.lv.buf[s * 256 + t] = key[half * 8 + s];
            __syncthreads();
            #pragma unroll
            for (int s = 0; s < 8; s++){
              ull part = sm.lv.buf[s * 256 + (t ^ tm)];
              ull A = key[half * 8 + s];
              ull mn = (A < part) ? A : part;
              ull mx = (A < part) ? part : A;
              key[half * 8 + s] = (up == low) ? mn : mx;
            }
          }
        } else if (j >= 4){
          int lm = sig >> 4;   // 1..32
          bool up = (((t << 4) & S) == 0);
          bool low = ((lane & lm) == 0);
          #pragma unroll
          for (int s = 0; s < 16; s++){
            unsigned klo = (unsigned)key[s];
            unsigned khi = (unsigned)(key[s] >> 32);
            unsigned plo = __shfl_xor(klo, lm, 64);
            unsigned phi = __shfl_xor(khi, lm, 64);
            ull part = ((ull)phi << 32) | (ull)plo;
            ull mn = (key[s] < part) ? key[s] : part;
            ull mx = (key[s] < part) ? part : key[s];
            key[s] = (up == low) ? mn : mx;
          }
        } else {
          switch (j){
            case 3:
              #pragma unroll
              for (int s = 0; s < 16; s++) if (!(s & 8)){
                int h = s | 8;
                bool up = ((((t << 4) | s) & S) == 0);
                ull A = key[s], B2 = key[h];
                ull mn = (A < B2) ? A : B2, mx = (A < B2) ? B2 : A;
                key[s] = up ? mn : mx; key[h] = up ? mx : mn;
              }
              break;
            case 2:
              #pragma unroll
              for (int s = 0; s < 16; s++) if (!(s & 4)){
                int h = s | 4;
                bool up = ((((t << 4) | s) & S) == 0);
                ull A = key[s], B2 = key[h];
                ull mn = (A < B2) ? A : B2, mx = (A < B2) ? B2 : A;
                key[s] = up ? mn : mx; key[h] = up ? mx : mn;
              }
              break;
            case 1:
              #pragma unroll
              for (int s = 0; s < 16; s++) if (!(s & 2)){
                int h = s | 2;
                bool up = ((((t << 4) | s) & S) == 0);
                ull A = key[s], B2 = key[h];
                ull mn = (A < B2) ? A : B2, mx = (A < B2) ? B2 : A;
                key[s] = up ? mn : mx; key[h] = up ? mx : mn;
              }
              break;
            default:
              #pragma unroll
              for (int s = 0; s < 16; s++) if (!(s & 1)){
                int h = s | 1;
                bool up = ((((t << 4) | s) & S) == 0);
                ull A = key[s], B2 = key[h];
                ull mn = (A < B2) ? A : B2, mx = (A < B2) ? B2 : A;
                key[s] = up ? mn : mx; key[h] = up ? mx : mn;
              }
              break;
          }
        }
      }
    }

    // --- epilogue: masks, exact integer prefix, jaccard ---
    int localm[16];
    int lsumt = 0;
    #pragma unroll
    for (int s = 0; s < 16; s++){
      int idx = (int)(unsigned)key[s];
      localm[s] = (lbl[b * NN + idx] == k + 1) ? 1 : 0;
      lsumt += localm[s];
    }
    int scan = lsumt;
    #pragma unroll
    for (int off = 1; off < 64; off <<= 1){
      int v = __shfl_up(scan, off, 64);
      if (lane >= off) scan += v;
    }
    if (lane == 63) sm.lv.wt[w] = scan;
    __syncthreads();
    int wbase = 0;
    #pragma unroll
    for (int w2 = 0; w2 < 4; w2++) if (w2 < w) wbase += sm.lv.wt[w2];
    int run = wbase + scan - lsumt;

    float cntk = ws[OFF_CNT + b * KK + k];
    float lsum = 0.f;
    #pragma unroll
    for (int s = 0; s < 16; s++){
      int p = (t << 4) + s;
      float jprev = (p == 0) ? 0.f
        : 1.f - (cntk - (float)run) / (cntk + (float)p - (float)run);
      int csum = run + localm[s];
      float jac = 1.f - (cntk - (float)csum) / (cntk + (float)(p + 1) - (float)csum);
      unsigned a2 = ~((unsigned)(key[s] >> 32));
      unsigned u2 = (a2 & 0x80000000u) ? (a2 ^ 0x80000000u) : ~a2;
      float ss = __uint_as_float(u2);
      lsum += fmaxf(ss, 0.f) * (jac - jprev);
      run = csum;
    }
    float tot = blockReduceSum(lsum, sm.lv.red);
    if (t == 0) atomicAdd(&accd[5], (double)tot);
  } else {
    // ================= BOUNDARY =================
    int qb = blockIdx.x - 64;
    int b = qb / 528;
    int rem = qb - b * 528;
    int ti = 0;
    while (rem >= 32 - ti){ rem -= 32 - ti; ti++; }
    int tj = ti + rem;
    bool diag = (ti == tj);
    int lane = t & 63, w = t >> 6;
    int lm = lane & 15;
    int rif = (lane >> 4) * 4;
    int lk = (lane >> 4) * 8;
    const ushort* E = EHg + (size_t)b * NN * DD;
    const float* NR = ws + OFF_NRM2 + b * NN;
    const int* LB = lbl + b * NN;

    bf16x8 a[2][2];
    #pragma unroll
    for (int rb = 0; rb < 2; rb++)
      #pragma unroll
      for (int kh = 0; kh < 2; kh++)
        a[rb][kh] = *(const bf16x8*)&E[(size_t)(ti * 128 + w * 32 + rb * 16 + lm) * DD + kh * 32 + lk];

    float nAr[8]; int lAr[8];
    #pragma unroll
    for (int rb = 0; rb < 2; rb++)
      #pragma unroll
      for (int r = 0; r < 4; r++){
        int gi = ti * 128 + w * 32 + rb * 16 + rif + r;
        nAr[rb * 4 + r] = NR[gi];
        lAr[rb * 4 + r] = LB[gi];
      }

    float sum = 0.f;
    #pragma unroll
    for (int pass = 0; pass < 2; pass++){
      float nBr[4]; int lBr[4];
      #pragma unroll
      for (int cb = 0; cb < 4; cb++){
        int gj = tj * 128 + (pass * 4 + cb) * 16 + lm;
        nBr[cb] = NR[gj];
        lBr[cb] = LB[gj];
      }
      f32x4 ac[2][4];
      #pragma unroll
      for (int rb = 0; rb < 2; rb++)
        #pragma unroll
        for (int cb = 0; cb < 4; cb++) ac[rb][cb] = (f32x4){0.f, 0.f, 0.f, 0.f};
      #pragma unroll
      for (int cb = 0; cb < 4; cb++){
        #pragma unroll
        for (int kh = 0; kh < 2; kh++){
          bf16x8 bb = *(const bf16x8*)&E[(size_t)(tj * 128 + (pass * 4 + cb) * 16 + lm) * DD + kh * 32 + lk];
          ac[0][cb] = __builtin_amdgcn_mfma_f32_16x16x32_bf16(a[0][kh], bb, ac[0][cb], 0, 0, 0);
          ac[1][cb] = __builtin_amdgcn_mfma_f32_16x16x32_bf16(a[1][kh], bb, ac[1][cb], 0, 0, 0);
        }
      }
      if (diag){
        #pragma unroll
        for (int rb = 0; rb < 2; rb++)
          #pragma unroll
          for (int cb = 0; cb < 4; cb++)
            #pragma unroll
            for (int r = 0; r < 4; r++){
              float d2 = nAr[rb * 4 + r] + nBr[cb] - 2.f * ac[rb][cb][r];
              float d = sqrtf(fmaxf(d2, 0.f));
              float f = (lAr[rb * 4 + r] == lBr[cb]) ? 1.5f : fmaxf(1.5f - d, 0.f);
              int gi = w * 32 + rb * 16 + rif + r;
              int gj = (pass * 4 + cb) * 16 + lm;
              if (gi < gj) sum += f;
            }
      } else {
        #pragma unroll
        for (int rb = 0; rb < 2; rb++)
          #pragma unroll
          for (int cb = 0; cb < 4; cb++)
            #pragma unroll
            for (int r = 0; r < 4; r++){
              float d2 = nAr[rb * 4 + r] + nBr[cb] - 2.f * ac[rb][cb][r];
              float d = sqrtf(fmaxf(d2, 0.f));
              float f = (lAr[rb * 4 + r] == lBr[cb]) ? 1.5f : fmaxf(1.5f - d, 0.f);
              sum += f;
            }
      }
    }
    float s = blockReduceSum(sum, sm.bd.red);
    if (t == 0) atomicAdd(&accd[4], (double)s);
  }
}

__global__ void kfinal(const double* __restrict__ acc, float* __restrict__ out){
  if (threadIdx.x == 0 && blockIdx.x == 0){
    double var_l  = acc[0] / (4.0 + 1e-6);
    double dist_l = acc[1] / (4.0 + 1e-6);
    double reg_l  = acc[2] / (4.0 + 1e-6);
    double cen_l  = acc[3] / 4.0;
    double bnd_l  = (2.0 * acc[4] + 1.5 * (double)NN * BB) / ((double)NN * NN * BB);
    double lov_l  = acc[5] / 4.0;
    double total = 0.1 * (var_l + dist_l + reg_l) + 0.1 * cen_l + 0.05 * bnd_l + 0.01 * lov_l;
    out[0] = (float)total; out[1] = (float)var_l; out[2] = (float)dist_l;
    out[3] = (float)reg_l; out[4] = (float)cen_l; out[5] = (float)bnd_l;
    out[6] = (float)lov_l;
  }
}

extern "C" void kernel_launch(void* const* d_in, const int* in_sizes, int n_in,
                              void* d_out, int out_size, void* d_ws, size_t ws_size,
                              hipStream_t stream){
  const float* pts = (const float*)d_in[0];
  const float* emb = (const float*)d_in[1];
  const int* lbl   = (const int*)d_in[2];
  float* out = (float*)d_out;
  float* ws = (float*)d_ws;
  double* acc = (double*)(ws + OFF_ACC);

  hipMemsetAsync(ws + OFF_FCSUM, 0, 4352 * sizeof(float), stream);
  hipLaunchKernelGGL(knormacc,  dim3(512), dim3(256), 0, stream, emb, pts, lbl, ws);
  hipLaunchKernelGGL(kcenters,  dim3(BB),  dim3(256), 0, stream, ws, acc);
  hipLaunchKernelGGL(kperpoint, dim3(64),  dim3(256), 0, stream, pts, lbl, ws, acc);
  hipLaunchKernelGGL(kfused,    dim3(64 + 528 * BB), dim3(256), 0, stream,
                     lbl, (const ushort*)(ws + OFF_EMBH), ws, acc);
  hipLaunchKernelGGL(kfinal,    dim3(1),   dim3(1),    0, stream, acc, out);
}

// Round 5
// 118.539 us; speedup vs baseline: 1.2851x; 1.2851x over previous
//
#include <hip/hip_runtime.h>

#define BB 4
#define NN 4096
#define DD 64
#define KK 16
#define NBUCK 2048

// ws float offsets
#define OFF_EMB   0u          // B*N*D = 1048576 (fp32 normalized emb)
#define OFF_NRM2  1310720u    // B*N   = 16384
#define OFF_FCSUM 1327104u    // B*K*D = 4096
#define OFF_GCSUM 1331200u    // B*K*3 = 192
#define OFF_CNT   1331392u    // B*K   = 64
#define OFF_FC    1331456u    // 4096
#define OFF_GC    1339648u    // 192
#define OFF_FCN2  1339840u    // 64
#define OFF_FCN   1339904u    // 64
#define OFF_CEN2  1339968u    // 64
#define OFF_GC2   1340032u    // 64
#define OFF_ACC   1340096u    // 8 doubles (16 floats), 8B aligned
#define OFF_EMBH  1340112u    // bf16 normalized emb
// acc: 0 var, 1 dist, 2 reg, 3 center, 4 boundary(raw upper-pair sum), 5 lovasz

typedef __attribute__((ext_vector_type(8))) short bf16x8;
typedef __attribute__((ext_vector_type(4))) float f32x4;
typedef unsigned long long ull;

__device__ __forceinline__ ushort f2bf(float x){
  unsigned u = __float_as_uint(x);
  return (ushort)((u + 0x7FFFu + ((u >> 16) & 1u)) >> 16);
}

__device__ __forceinline__ float blockReduceSum(float v, float* sbuf){
  int t = threadIdx.x;
  #pragma unroll
  for (int off = 32; off > 0; off >>= 1) v += __shfl_xor(v, off, 64);
  if ((t & 63) == 0) sbuf[t >> 6] = v;
  __syncthreads();
  float s = 0.f;
  if (t == 0){
    int nw = blockDim.x >> 6;
    for (int i = 0; i < nw; i++) s += sbuf[i];
  }
  __syncthreads();
  return s;
}

// Normalize embeddings, per-instance sums. One wave handles 8 points; lane = dim.
__global__ void knormacc(const float* __restrict__ emb, const float* __restrict__ pts,
                         const int* __restrict__ lbl, float* __restrict__ ws){
  __shared__ float fcl[KK * DD];
  __shared__ float gcl[KK * 3];
  __shared__ float cntl[KK];
  int t = threadIdx.x;
  if (blockIdx.x == 0 && t < 16) ws[OFF_ACC + t] = 0.f;
  for (int i = t; i < KK * DD; i += 256) fcl[i] = 0.f;
  if (t < KK * 3) gcl[t] = 0.f;
  if (t < KK) cntl[t] = 0.f;
  __syncthreads();

  int lane = t & 63, w = t >> 6;
  int b = blockIdx.x >> 7;
  int local = blockIdx.x & 127;
  int base = local * 32 + w * 8;
  const float* E = emb + (size_t)b * NN * DD;
  float* EN = ws + OFF_EMB + (size_t)b * NN * DD;
  ushort* EH = (ushort*)(ws + OFF_EMBH) + (size_t)b * NN * DD;

  for (int i = 0; i < 8; i++){
    int n = base + i;
    float v = E[(size_t)n * DD + lane];
    float ss = v * v;
    #pragma unroll
    for (int off = 1; off < 64; off <<= 1) ss += __shfl_xor(ss, off, 64);
    float nrm = sqrtf(ss);
    float scale = 1.0f / fmaxf(nrm, 1e-12f);
    float vn = v * scale;
    EN[(size_t)n * DD + lane] = vn;
    EH[(size_t)n * DD + lane] = f2bf(vn);
    if (lane == 0) ws[OFF_NRM2 + b * NN + n] = ss * scale * scale;
    int l = lbl[b * NN + n];
    if (l >= 1 && l <= KK){
      int k = l - 1;
      atomicAdd(&fcl[k * DD + lane], vn);
      if (lane < 3) atomicAdd(&gcl[k * 3 + lane], pts[((size_t)b * NN + n) * 3 + lane]);
      if (lane == 0) atomicAdd(&cntl[k], 1.0f);
    }
  }
  __syncthreads();
  for (int i = t; i < KK * DD; i += 256) atomicAdd(&ws[OFF_FCSUM + b * KK * DD + i], fcl[i]);
  if (t < KK * 3) atomicAdd(&ws[OFF_GCSUM + b * KK * 3 + t], gcl[t]);
  if (t < KK)     atomicAdd(&ws[OFF_CNT + b * KK + t], cntl[t]);
}

// Finalize centers, dist loss, reg loss. One block per batch; lane = dim, wave = k-group.
__global__ void kcenters(float* __restrict__ ws, double* __restrict__ acc){
  __shared__ float cenS[KK][DD];
  __shared__ float cen2S[KK];
  __shared__ float red[16];
  int b = blockIdx.x, t = threadIdx.x;
  int lane = t & 63, w = t >> 6;
  for (int k = w; k < KK; k += 4){
    float c = ws[OFF_CNT + b * KK + k];
    float inv_c = 1.f / c;
    float f = ws[OFF_FCSUM + (b * KK + k) * DD + lane] * inv_c;
    ws[OFF_FC + (b * KK + k) * DD + lane] = f;
    float n2 = f * f;
    #pragma unroll
    for (int off = 1; off < 64; off <<= 1) n2 += __shfl_xor(n2, off, 64);
    float fn = sqrtf(n2);
    float inv = 1.f / fmaxf(fn, 1e-12f);
    float ce = f * inv;
    cenS[k][lane] = ce;
    float c2 = ce * ce;
    #pragma unroll
    for (int off = 1; off < 64; off <<= 1) c2 += __shfl_xor(c2, off, 64);
    float g = (lane < 3) ? ws[OFF_GCSUM + (b * KK + k) * 3 + lane] * inv_c : 0.f;
    if (lane < 3) ws[OFF_GC + (b * KK + k) * 3 + lane] = g;
    float g2 = g * g;
    g2 += __shfl_xor(g2, 1, 64);
    g2 += __shfl_xor(g2, 2, 64);
    if (lane == 0){
      ws[OFF_FCN2 + b * KK + k] = n2;
      ws[OFF_FCN + b * KK + k] = fn;
      ws[OFF_CEN2 + b * KK + k] = c2;
      ws[OFF_GC2 + b * KK + k] = g2;
      cen2S[k] = c2;
    }
  }
  __syncthreads();
  int i = t >> 4, j = t & 15;
  float v = 0.f;
  if (i != j){
    float dot = 0.f;
    #pragma unroll
    for (int d = 0; d < DD; d++) dot += cenS[i][d] * cenS[j][d];
    float cd = sqrtf(fmaxf(cen2S[i] + cen2S[j] - 2.f * dot, 0.f));
    v = fmaxf(3.f - cd, 0.f);
  }
  float s = blockReduceSum(v, red);
  if (t == 0){
    atomicAdd(&acc[1], (double)(s / 240.f));
    float s2 = 0.f;
    for (int k = 0; k < KK; k++) s2 += cen2S[k];
    atomicAdd(&acc[2], (double)(sqrtf(s2) * 0.001f));
  }
}

// Fused: blocks 0..63 = lovasz-histogram + var + center (one per (b,k));
//        blocks 64.. = boundary 128x128 MFMA tiles.
__global__ __launch_bounds__(256, 8) void kfused(const int* __restrict__ lbl,
                                                 const ushort* __restrict__ EHg,
                                                 const float* __restrict__ pts,
                                                 float* __restrict__ ws,
                                                 double* __restrict__ accd){
  __shared__ union SMem {
    struct { unsigned hist[NBUCK]; float ssum[NBUCK]; float fc[DD];
             unsigned wsum[4]; float red[16]; } lv;   // ~16.6 KB
    struct { float red[16]; } bd;
  } sm;
  int t = threadIdx.x;

  if (blockIdx.x < 64){
    // ======== LOVASZ (histogram, tie-exact) + VAR + CENTER ========
    int bk = blockIdx.x;
    int b = bk >> 4, k = bk & 15;
    int lane = t & 63, w = t >> 6;
    for (int i = t; i < NBUCK; i += 256){ sm.lv.hist[i] = 0u; sm.lv.ssum[i] = 0.f; }
    if (t < DD) sm.lv.fc[t] = ws[OFF_FC + (size_t)(b * KK + k) * DD + t];
    float C     = ws[OFF_CNT  + b * KK + k];
    float fcn   = ws[OFF_FCN  + b * KK + k];
    float fcn2  = ws[OFF_FCN2 + b * KK + k];
    float cen2  = ws[OFF_CEN2 + b * KK + k];
    float gc2   = ws[OFF_GC2  + b * KK + k];
    float g0    = ws[OFF_GC + (b * KK + k) * 3 + 0];
    float g1    = ws[OFF_GC + (b * KK + k) * 3 + 1];
    float g2v   = ws[OFF_GC + (b * KK + k) * 3 + 2];
    float mfn   = fmaxf(fcn, 1e-8f);
    float invfc = 1.f / fmaxf(fcn, 1e-12f);
    float invC  = 1.f / C;
    __syncthreads();

    const float* EN = ws + OFF_EMB + (size_t)b * NN * DD;
    const float* NR = ws + OFF_NRM2 + b * NN;
    const int* LB = lbl + b * NN;
    float varA = 0.f, cenA = 0.f;

    for (int c = 0; c < 16; c++){
      int n = c * 256 + t;
      const float4* e4 = (const float4*)&EN[(size_t)n * DD];
      float dx = 0.f, dy = 0.f, dz = 0.f, dw = 0.f;
      #pragma unroll
      for (int i = 0; i < 16; i++){
        float4 e = e4[i];
        float4 f = ((const float4*)sm.lv.fc)[i];
        dx += e.x * f.x; dy += e.y * f.y; dz += e.z * f.z; dw += e.w * f.w;
      }
      float dot = (dx + dy) + (dz + dw);
      float nrm2 = NR[n];
      float nrm = sqrtf(nrm2);
      float sim = dot / (fmaxf(nrm, 1e-8f) * mfn);
      int m = (LB[n] == k + 1) ? 1 : 0;
      if (sim > 0.f){
        int q = (int)(sim * (float)NBUCK);
        q = q > NBUCK - 1 ? NBUCK - 1 : q;
        int qi = NBUCK - 1 - q;
        atomicAdd(&sm.lv.hist[qi], 1u + ((unsigned)m << 16));
        atomicAdd(&sm.lv.ssum[qi], sim);
      }
      if (m){
        float dotc = dot * invfc;
        float dnc = sqrtf(fmaxf(nrm2 + cen2 - 2.f * dotc, 0.f));
        varA += fmaxf(dnc - 0.5f, 0.f);
        float fd = sqrtf(fmaxf(nrm2 + fcn2 - 2.f * dot, 0.f));
        float p0 = pts[((size_t)b * NN + n) * 3 + 0];
        float p1 = pts[((size_t)b * NN + n) * 3 + 1];
        float p2 = pts[((size_t)b * NN + n) * 3 + 2];
        float sd2 = p0 * p0 + p1 * p1 + p2 * p2 + gc2 - 2.f * (p0 * g0 + p1 * g1 + p2 * g2v);
        cenA += sqrtf(fmaxf(sd2, 0.f)) * fd;
      }
    }
    __syncthreads();

    // packed exclusive scan over buckets (ascending qi = descending sim)
    int base = t * 8;
    unsigned loc[8];
    unsigned run = 0;
    #pragma unroll
    for (int i = 0; i < 8; i++){ loc[i] = run; run += sm.lv.hist[base + i]; }
    unsigned tot = run, sc = tot;
    #pragma unroll
    for (int off = 1; off < 64; off <<= 1){
      unsigned v = __shfl_up(sc, off, 64);
      if (lane >= off) sc += v;
    }
    if (lane == 63) sm.lv.wsum[w] = sc;
    __syncthreads();
    unsigned wbase = 0;
    #pragma unroll
    for (int w2 = 0; w2 < 4; w2++) if (w2 < w) wbase += sm.lv.wsum[w2];
    unsigned ex = wbase + sc - tot;

    float contrib = 0.f;
    #pragma unroll
    for (int i = 0; i < 8; i++){
      unsigned h = sm.lv.hist[base + i];
      unsigned g = h & 0xFFFFu, mu = h >> 16;
      if (g){
        unsigned pre = ex + loc[i];
        float i0 = (float)(pre & 0xFFFFu), c0 = (float)(pre >> 16);
        float i1 = i0 + (float)g, c1 = c0 + (float)mu;
        float jac0 = 1.f - (C - c0) / (C + i0 - c0);
        float jac1 = 1.f - (C - c1) / (C + i1 - c1);
        contrib += sm.lv.ssum[base + i] * (jac1 - jac0) / (float)g;
      }
    }
    __syncthreads();
    float vs = blockReduceSum(varA * invC, sm.lv.red);
    if (t == 0) atomicAdd(&accd[0], (double)vs);
    float cs = blockReduceSum(cenA * invC, sm.lv.red);
    if (t == 0) atomicAdd(&accd[3], (double)cs);
    float ls = blockReduceSum(contrib, sm.lv.red);
    if (t == 0) atomicAdd(&accd[5], (double)ls);
  } else {
    // ================= BOUNDARY =================
    int qb = blockIdx.x - 64;
    int b = qb / 528;
    int rem = qb - b * 528;
    int ti = 0;
    while (rem >= 32 - ti){ rem -= 32 - ti; ti++; }
    int tj = ti + rem;
    bool diag = (ti == tj);
    int lane = t & 63, w = t >> 6;
    int lm = lane & 15;
    int rif = (lane >> 4) * 4;
    int lk = (lane >> 4) * 8;
    const ushort* E = EHg + (size_t)b * NN * DD;
    const float* NR = ws + OFF_NRM2 + b * NN;
    const int* LB = lbl + b * NN;

    bf16x8 a[2][2];
    #pragma unroll
    for (int rb = 0; rb < 2; rb++)
      #pragma unroll
      for (int kh = 0; kh < 2; kh++)
        a[rb][kh] = *(const bf16x8*)&E[(size_t)(ti * 128 + w * 32 + rb * 16 + lm) * DD + kh * 32 + lk];

    float nAr[8]; int lAr[8];
    #pragma unroll
    for (int rb = 0; rb < 2; rb++)
      #pragma unroll
      for (int r = 0; r < 4; r++){
        int gi = ti * 128 + w * 32 + rb * 16 + rif + r;
        nAr[rb * 4 + r] = NR[gi];
        lAr[rb * 4 + r] = LB[gi];
      }

    float sum = 0.f;
    #pragma unroll
    for (int pass = 0; pass < 2; pass++){
      float nBr[4]; int lBr[4];
      #pragma unroll
      for (int cb = 0; cb < 4; cb++){
        int gj = tj * 128 + (pass * 4 + cb) * 16 + lm;
        nBr[cb] = NR[gj];
        lBr[cb] = LB[gj];
      }
      f32x4 ac[2][4];
      #pragma unroll
      for (int rb = 0; rb < 2; rb++)
        #pragma unroll
        for (int cb = 0; cb < 4; cb++) ac[rb][cb] = (f32x4){0.f, 0.f, 0.f, 0.f};
      #pragma unroll
      for (int cb = 0; cb < 4; cb++){
        #pragma unroll
        for (int kh = 0; kh < 2; kh++){
          bf16x8 bb = *(const bf16x8*)&E[(size_t)(tj * 128 + (pass * 4 + cb) * 16 + lm) * DD + kh * 32 + lk];
          ac[0][cb] = __builtin_amdgcn_mfma_f32_16x16x32_bf16(a[0][kh], bb, ac[0][cb], 0, 0, 0);
          ac[1][cb] = __builtin_amdgcn_mfma_f32_16x16x32_bf16(a[1][kh], bb, ac[1][cb], 0, 0, 0);
        }
      }
      if (diag){
        #pragma unroll
        for (int rb = 0; rb < 2; rb++)
          #pragma unroll
          for (int cb = 0; cb < 4; cb++)
            #pragma unroll
            for (int r = 0; r < 4; r++){
              float d2 = nAr[rb * 4 + r] + nBr[cb] - 2.f * ac[rb][cb][r];
              float d = sqrtf(fmaxf(d2, 0.f));
              float f = (lAr[rb * 4 + r] == lBr[cb]) ? 1.5f : fmaxf(1.5f - d, 0.f);
              int gi = w * 32 + rb * 16 + rif + r;
              int gj = (pass * 4 + cb) * 16 + lm;
              if (gi < gj) sum += f;
            }
      } else {
        #pragma unroll
        for (int rb = 0; rb < 2; rb++)
          #pragma unroll
          for (int cb = 0; cb < 4; cb++)
            #pragma unroll
            for (int r = 0; r < 4; r++){
              float d2 = nAr[rb * 4 + r] + nBr[cb] - 2.f * ac[rb][cb][r];
              float d = sqrtf(fmaxf(d2, 0.f));
              float f = (lAr[rb * 4 + r] == lBr[cb]) ? 1.5f : fmaxf(1.5f - d, 0.f);
              sum += f;
            }
      }
    }
    float s = blockReduceSum(sum, sm.bd.red);
    if (t == 0) atomicAdd(&accd[4], (double)s);
  }
}

__global__ void kfinal(const double* __restrict__ acc, float* __restrict__ out){
  if (threadIdx.x == 0 && blockIdx.x == 0){
    double var_l  = acc[0] / (4.0 + 1e-6);
    double dist_l = acc[1] / (4.0 + 1e-6);
    double reg_l  = acc[2] / (4.0 + 1e-6);
    double cen_l  = acc[3] / 4.0;
    double bnd_l  = (2.0 * acc[4] + 1.5 * (double)NN * BB) / ((double)NN * NN * BB);
    double lov_l  = acc[5] / 4.0;
    double total = 0.1 * (var_l + dist_l + reg_l) + 0.1 * cen_l + 0.05 * bnd_l + 0.01 * lov_l;
    out[0] = (float)total; out[1] = (float)var_l; out[2] = (float)dist_l;
    out[3] = (float)reg_l; out[4] = (float)cen_l; out[5] = (float)bnd_l;
    out[6] = (float)lov_l;
  }
}

extern "C" void kernel_launch(void* const* d_in, const int* in_sizes, int n_in,
                              void* d_out, int out_size, void* d_ws, size_t ws_size,
                              hipStream_t stream){
  const float* pts = (const float*)d_in[0];
  const float* emb = (const float*)d_in[1];
  const int* lbl   = (const int*)d_in[2];
  float* out = (float*)d_out;
  float* ws = (float*)d_ws;
  double* acc = (double*)(ws + OFF_ACC);

  hipMemsetAsync(ws + OFF_FCSUM, 0, 4352 * sizeof(float), stream);
  hipLaunchKernelGGL(knormacc, dim3(512), dim3(256), 0, stream, emb, pts, lbl, ws);
  hipLaunchKernelGGL(kcenters, dim3(BB),  dim3(256), 0, stream, ws, acc);
  hipLaunchKernelGGL(kfused,   dim3(64 + 528 * BB), dim3(256), 0, stream,
                     lbl, (const ushort*)(ws + OFF_EMBH), pts, ws, acc);
  hipLaunchKernelGGL(kfinal,   dim3(1),   dim3(1),    0, stream, acc, out);
}

// Round 6
// 93.919 us; speedup vs baseline: 1.6219x; 1.2621x over previous
//
#include <hip/hip_runtime.h>

#define BB 4
#define NN 4096
#define DD 64
#define KK 16
#define NBUCK 2048

// ws float offsets
#define OFF_EMB   0u          // B*N*D = 1048576 (fp32 normalized emb)
#define OFF_NRM2  1310720u    // B*N   = 16384
#define OFF_FCSUM 1327104u    // B*K*D = 4096
#define OFF_GCSUM 1331200u    // B*K*3 = 192
#define OFF_CNT   1331392u    // B*K   = 64
#define OFF_FC    1331456u    // 4096
#define OFF_GC    1339648u    // 192
#define OFF_FCN2  1339840u    // 64
#define OFF_FCN   1339904u    // 64
#define OFF_CEN2  1339968u    // 64
#define OFF_GC2   1340032u    // 64
#define OFF_ACC   1340096u    // 8 doubles (16 floats), 8B aligned
#define OFF_EMBH  1340112u    // bf16 normalized emb
// acc: 0 var, 1 dist, 2 reg, 3 center, 4 boundary(raw upper-pair sum), 5 lovasz

typedef __attribute__((ext_vector_type(8))) short bf16x8;
typedef __attribute__((ext_vector_type(4))) float f32x4;
typedef unsigned long long ull;

__device__ __forceinline__ ushort f2bf(float x){
  unsigned u = __float_as_uint(x);
  return (ushort)((u + 0x7FFFu + ((u >> 16) & 1u)) >> 16);
}

__device__ __forceinline__ float blockReduceSum(float v, float* sbuf){
  int t = threadIdx.x;
  #pragma unroll
  for (int off = 32; off > 0; off >>= 1) v += __shfl_xor(v, off, 64);
  if ((t & 63) == 0) sbuf[t >> 6] = v;
  __syncthreads();
  float s = 0.f;
  if (t == 0){
    int nw = blockDim.x >> 6;
    for (int i = 0; i < nw; i++) s += sbuf[i];
  }
  __syncthreads();
  return s;
}

// Normalize embeddings, per-instance sums. One wave handles 8 points; lane = dim.
__global__ void knormacc(const float* __restrict__ emb, const float* __restrict__ pts,
                         const int* __restrict__ lbl, float* __restrict__ ws){
  __shared__ float fcl[KK * DD];
  __shared__ float gcl[KK * 3];
  __shared__ float cntl[KK];
  int t = threadIdx.x;
  if (blockIdx.x == 0 && t < 16) ws[OFF_ACC + t] = 0.f;
  for (int i = t; i < KK * DD; i += 256) fcl[i] = 0.f;
  if (t < KK * 3) gcl[t] = 0.f;
  if (t < KK) cntl[t] = 0.f;
  __syncthreads();

  int lane = t & 63, w = t >> 6;
  int b = blockIdx.x >> 7;
  int local = blockIdx.x & 127;
  int base = local * 32 + w * 8;
  const float* E = emb + (size_t)b * NN * DD;
  float* EN = ws + OFF_EMB + (size_t)b * NN * DD;
  ushort* EH = (ushort*)(ws + OFF_EMBH) + (size_t)b * NN * DD;

  for (int i = 0; i < 8; i++){
    int n = base + i;
    float v = E[(size_t)n * DD + lane];
    float ss = v * v;
    #pragma unroll
    for (int off = 1; off < 64; off <<= 1) ss += __shfl_xor(ss, off, 64);
    float nrm = sqrtf(ss);
    float scale = 1.0f / fmaxf(nrm, 1e-12f);
    float vn = v * scale;
    EN[(size_t)n * DD + lane] = vn;
    EH[(size_t)n * DD + lane] = f2bf(vn);
    if (lane == 0) ws[OFF_NRM2 + b * NN + n] = ss * scale * scale;
    int l = lbl[b * NN + n];
    if (l >= 1 && l <= KK){
      int k = l - 1;
      atomicAdd(&fcl[k * DD + lane], vn);
      if (lane < 3) atomicAdd(&gcl[k * 3 + lane], pts[((size_t)b * NN + n) * 3 + lane]);
      if (lane == 0) atomicAdd(&cntl[k], 1.0f);
    }
  }
  __syncthreads();
  for (int i = t; i < KK * DD; i += 256) atomicAdd(&ws[OFF_FCSUM + b * KK * DD + i], fcl[i]);
  if (t < KK * 3) atomicAdd(&ws[OFF_GCSUM + b * KK * 3 + t], gcl[t]);
  if (t < KK)     atomicAdd(&ws[OFF_CNT + b * KK + t], cntl[t]);
}

// Finalize centers, dist loss, reg loss. One block per batch; lane = dim, wave = k-group.
__global__ void kcenters(float* __restrict__ ws, double* __restrict__ acc){
  __shared__ float cenS[KK][DD];
  __shared__ float cen2S[KK];
  __shared__ float red[16];
  int b = blockIdx.x, t = threadIdx.x;
  int lane = t & 63, w = t >> 6;
  for (int k = w; k < KK; k += 4){
    float c = ws[OFF_CNT + b * KK + k];
    float inv_c = 1.f / c;
    float f = ws[OFF_FCSUM + (b * KK + k) * DD + lane] * inv_c;
    ws[OFF_FC + (b * KK + k) * DD + lane] = f;
    float n2 = f * f;
    #pragma unroll
    for (int off = 1; off < 64; off <<= 1) n2 += __shfl_xor(n2, off, 64);
    float fn = sqrtf(n2);
    float inv = 1.f / fmaxf(fn, 1e-12f);
    float ce = f * inv;
    cenS[k][lane] = ce;
    float c2 = ce * ce;
    #pragma unroll
    for (int off = 1; off < 64; off <<= 1) c2 += __shfl_xor(c2, off, 64);
    float g = (lane < 3) ? ws[OFF_GCSUM + (b * KK + k) * 3 + lane] * inv_c : 0.f;
    if (lane < 3) ws[OFF_GC + (b * KK + k) * 3 + lane] = g;
    float g2 = g * g;
    g2 += __shfl_xor(g2, 1, 64);
    g2 += __shfl_xor(g2, 2, 64);
    if (lane == 0){
      ws[OFF_FCN2 + b * KK + k] = n2;
      ws[OFF_FCN + b * KK + k] = fn;
      ws[OFF_CEN2 + b * KK + k] = c2;
      ws[OFF_GC2 + b * KK + k] = g2;
      cen2S[k] = c2;
    }
  }
  __syncthreads();
  int i = t >> 4, j = t & 15;
  float v = 0.f;
  if (i != j){
    float dot = 0.f;
    #pragma unroll
    for (int d = 0; d < DD; d++) dot += cenS[i][d] * cenS[j][d];
    float cd = sqrtf(fmaxf(cen2S[i] + cen2S[j] - 2.f * dot, 0.f));
    v = fmaxf(3.f - cd, 0.f);
  }
  float s = blockReduceSum(v, red);
  if (t == 0){
    atomicAdd(&acc[1], (double)(s / 240.f));
    float s2 = 0.f;
    for (int k = 0; k < KK; k++) s2 += cen2S[k];
    atomicAdd(&acc[2], (double)(sqrtf(s2) * 0.001f));
  }
}

// Fused: blocks 0..63 = lovasz-histogram + var + center (one per (b,k));
//        blocks 64.. = boundary 128x128 MFMA tiles.
// launch_bounds(256,4): 128-VGPR cap. (256,8) capped at 64 and spilled the
// boundary branch's MFMA operand/acc arrays -> 117 MB scratch traffic (R5).
__global__ __launch_bounds__(256, 4) void kfused(const int* __restrict__ lbl,
                                                 const ushort* __restrict__ EHg,
                                                 const float* __restrict__ pts,
                                                 float* __restrict__ ws,
                                                 double* __restrict__ accd){
  __shared__ union SMem {
    struct { unsigned hist[NBUCK]; float ssum[NBUCK]; float fc[DD];
             unsigned wsum[4]; float red[16]; } lv;   // ~16.6 KB
    struct { float red[16]; } bd;
  } sm;
  int t = threadIdx.x;

  if (blockIdx.x < 64){
    // ======== LOVASZ (histogram, tie-exact) + VAR + CENTER ========
    int bk = blockIdx.x;
    int b = bk >> 4, k = bk & 15;
    int lane = t & 63, w = t >> 6;
    for (int i = t; i < NBUCK; i += 256){ sm.lv.hist[i] = 0u; sm.lv.ssum[i] = 0.f; }
    if (t < DD) sm.lv.fc[t] = ws[OFF_FC + (size_t)(b * KK + k) * DD + t];
    float C     = ws[OFF_CNT  + b * KK + k];
    float fcn   = ws[OFF_FCN  + b * KK + k];
    float fcn2  = ws[OFF_FCN2 + b * KK + k];
    float cen2  = ws[OFF_CEN2 + b * KK + k];
    float gc2   = ws[OFF_GC2  + b * KK + k];
    float g0    = ws[OFF_GC + (b * KK + k) * 3 + 0];
    float g1    = ws[OFF_GC + (b * KK + k) * 3 + 1];
    float g2v   = ws[OFF_GC + (b * KK + k) * 3 + 2];
    float mfn   = fmaxf(fcn, 1e-8f);
    float invfc = 1.f / fmaxf(fcn, 1e-12f);
    float invC  = 1.f / C;
    __syncthreads();

    const float* EN = ws + OFF_EMB + (size_t)b * NN * DD;
    const float* NR = ws + OFF_NRM2 + b * NN;
    const int* LB = lbl + b * NN;
    float varA = 0.f, cenA = 0.f;

    for (int c = 0; c < 16; c++){
      int n = c * 256 + t;
      const float4* e4 = (const float4*)&EN[(size_t)n * DD];
      float dx = 0.f, dy = 0.f, dz = 0.f, dw = 0.f;
      #pragma unroll
      for (int i = 0; i < 16; i++){
        float4 e = e4[i];
        float4 f = ((const float4*)sm.lv.fc)[i];
        dx += e.x * f.x; dy += e.y * f.y; dz += e.z * f.z; dw += e.w * f.w;
      }
      float dot = (dx + dy) + (dz + dw);
      float nrm2 = NR[n];
      float nrm = sqrtf(nrm2);
      float sim = dot / (fmaxf(nrm, 1e-8f) * mfn);
      int m = (LB[n] == k + 1) ? 1 : 0;
      if (sim > 0.f){
        int q = (int)(sim * (float)NBUCK);
        q = q > NBUCK - 1 ? NBUCK - 1 : q;
        int qi = NBUCK - 1 - q;
        atomicAdd(&sm.lv.hist[qi], 1u + ((unsigned)m << 16));
        atomicAdd(&sm.lv.ssum[qi], sim);
      }
      if (m){
        float dotc = dot * invfc;
        float dnc = sqrtf(fmaxf(nrm2 + cen2 - 2.f * dotc, 0.f));
        varA += fmaxf(dnc - 0.5f, 0.f);
        float fd = sqrtf(fmaxf(nrm2 + fcn2 - 2.f * dot, 0.f));
        float p0 = pts[((size_t)b * NN + n) * 3 + 0];
        float p1 = pts[((size_t)b * NN + n) * 3 + 1];
        float p2 = pts[((size_t)b * NN + n) * 3 + 2];
        float sd2 = p0 * p0 + p1 * p1 + p2 * p2 + gc2 - 2.f * (p0 * g0 + p1 * g1 + p2 * g2v);
        cenA += sqrtf(fmaxf(sd2, 0.f)) * fd;
      }
    }
    __syncthreads();

    // packed exclusive scan over buckets (ascending qi = descending sim)
    int base = t * 8;
    unsigned loc[8];
    unsigned run = 0;
    #pragma unroll
    for (int i = 0; i < 8; i++){ loc[i] = run; run += sm.lv.hist[base + i]; }
    unsigned tot = run, sc = tot;
    #pragma unroll
    for (int off = 1; off < 64; off <<= 1){
      unsigned v = __shfl_up(sc, off, 64);
      if (lane >= off) sc += v;
    }
    if (lane == 63) sm.lv.wsum[w] = sc;
    __syncthreads();
    unsigned wbase = 0;
    #pragma unroll
    for (int w2 = 0; w2 < 4; w2++) if (w2 < w) wbase += sm.lv.wsum[w2];
    unsigned ex = wbase + sc - tot;

    float contrib = 0.f;
    #pragma unroll
    for (int i = 0; i < 8; i++){
      unsigned h = sm.lv.hist[base + i];
      unsigned g = h & 0xFFFFu, mu = h >> 16;
      if (g){
        unsigned pre = ex + loc[i];
        float i0 = (float)(pre & 0xFFFFu), c0 = (float)(pre >> 16);
        float i1 = i0 + (float)g, c1 = c0 + (float)mu;
        float jac0 = 1.f - (C - c0) / (C + i0 - c0);
        float jac1 = 1.f - (C - c1) / (C + i1 - c1);
        contrib += sm.lv.ssum[base + i] * (jac1 - jac0) / (float)g;
      }
    }
    __syncthreads();
    float vs = blockReduceSum(varA * invC, sm.lv.red);
    if (t == 0) atomicAdd(&accd[0], (double)vs);
    float cs = blockReduceSum(cenA * invC, sm.lv.red);
    if (t == 0) atomicAdd(&accd[3], (double)cs);
    float ls = blockReduceSum(contrib, sm.lv.red);
    if (t == 0) atomicAdd(&accd[5], (double)ls);
  } else {
    // ================= BOUNDARY =================
    int qb = blockIdx.x - 64;
    int b = qb / 528;
    int rem = qb - b * 528;
    int ti = 0;
    while (rem >= 32 - ti){ rem -= 32 - ti; ti++; }
    int tj = ti + rem;
    bool diag = (ti == tj);
    int lane = t & 63, w = t >> 6;
    int lm = lane & 15;
    int rif = (lane >> 4) * 4;
    int lk = (lane >> 4) * 8;
    const ushort* E = EHg + (size_t)b * NN * DD;
    const float* NR = ws + OFF_NRM2 + b * NN;
    const int* LB = lbl + b * NN;

    bf16x8 a[2][2];
    #pragma unroll
    for (int rb = 0; rb < 2; rb++)
      #pragma unroll
      for (int kh = 0; kh < 2; kh++)
        a[rb][kh] = *(const bf16x8*)&E[(size_t)(ti * 128 + w * 32 + rb * 16 + lm) * DD + kh * 32 + lk];

    float nAr[8]; int lAr[8];
    #pragma unroll
    for (int rb = 0; rb < 2; rb++)
      #pragma unroll
      for (int r = 0; r < 4; r++){
        int gi = ti * 128 + w * 32 + rb * 16 + rif + r;
        nAr[rb * 4 + r] = NR[gi];
        lAr[rb * 4 + r] = LB[gi];
      }

    float sum = 0.f;
    #pragma unroll
    for (int pass = 0; pass < 2; pass++){
      float nBr[4]; int lBr[4];
      #pragma unroll
      for (int cb = 0; cb < 4; cb++){
        int gj = tj * 128 + (pass * 4 + cb) * 16 + lm;
        nBr[cb] = NR[gj];
        lBr[cb] = LB[gj];
      }
      f32x4 ac[2][4];
      #pragma unroll
      for (int rb = 0; rb < 2; rb++)
        #pragma unroll
        for (int cb = 0; cb < 4; cb++) ac[rb][cb] = (f32x4){0.f, 0.f, 0.f, 0.f};
      #pragma unroll
      for (int cb = 0; cb < 4; cb++){
        #pragma unroll
        for (int kh = 0; kh < 2; kh++){
          bf16x8 bb = *(const bf16x8*)&E[(size_t)(tj * 128 + (pass * 4 + cb) * 16 + lm) * DD + kh * 32 + lk];
          ac[0][cb] = __builtin_amdgcn_mfma_f32_16x16x32_bf16(a[0][kh], bb, ac[0][cb], 0, 0, 0);
          ac[1][cb] = __builtin_amdgcn_mfma_f32_16x16x32_bf16(a[1][kh], bb, ac[1][cb], 0, 0, 0);
        }
      }
      if (diag){
        #pragma unroll
        for (int rb = 0; rb < 2; rb++)
          #pragma unroll
          for (int cb = 0; cb < 4; cb++)
            #pragma unroll
            for (int r = 0; r < 4; r++){
              float d2 = nAr[rb * 4 + r] + nBr[cb] - 2.f * ac[rb][cb][r];
              float d = sqrtf(fmaxf(d2, 0.f));
              float f = (lAr[rb * 4 + r] == lBr[cb]) ? 1.5f : fmaxf(1.5f - d, 0.f);
              int gi = w * 32 + rb * 16 + rif + r;
              int gj = (pass * 4 + cb) * 16 + lm;
              if (gi < gj) sum += f;
            }
      } else {
        #pragma unroll
        for (int rb = 0; rb < 2; rb++)
          #pragma unroll
          for (int cb = 0; cb < 4; cb++)
            #pragma unroll
            for (int r = 0; r < 4; r++){
              float d2 = nAr[rb * 4 + r] + nBr[cb] - 2.f * ac[rb][cb][r];
              float d = sqrtf(fmaxf(d2, 0.f));
              float f = (lAr[rb * 4 + r] == lBr[cb]) ? 1.5f : fmaxf(1.5f - d, 0.f);
              sum += f;
            }
      }
    }
    float s = blockReduceSum(sum, sm.bd.red);
    if (t == 0) atomicAdd(&accd[4], (double)s);
  }
}

__global__ void kfinal(const double* __restrict__ acc, float* __restrict__ out){
  if (threadIdx.x == 0 && blockIdx.x == 0){
    double var_l  = acc[0] / (4.0 + 1e-6);
    double dist_l = acc[1] / (4.0 + 1e-6);
    double reg_l  = acc[2] / (4.0 + 1e-6);
    double cen_l  = acc[3] / 4.0;
    double bnd_l  = (2.0 * acc[4] + 1.5 * (double)NN * BB) / ((double)NN * NN * BB);
    double lov_l  = acc[5] / 4.0;
    double total = 0.1 * (var_l + dist_l + reg_l) + 0.1 * cen_l + 0.05 * bnd_l + 0.01 * lov_l;
    out[0] = (float)total; out[1] = (float)var_l; out[2] = (float)dist_l;
    out[3] = (float)reg_l; out[4] = (float)cen_l; out[5] = (float)bnd_l;
    out[6] = (float)lov_l;
  }
}

extern "C" void kernel_launch(void* const* d_in, const int* in_sizes, int n_in,
                              void* d_out, int out_size, void* d_ws, size_t ws_size,
                              hipStream_t stream){
  const float* pts = (const float*)d_in[0];
  const float* emb = (const float*)d_in[1];
  const int* lbl   = (const int*)d_in[2];
  float* out = (float*)d_out;
  float* ws = (float*)d_ws;
  double* acc = (double*)(ws + OFF_ACC);

  hipMemsetAsync(ws + OFF_FCSUM, 0, 4352 * sizeof(float), stream);
  hipLaunchKernelGGL(knormacc, dim3(512), dim3(256), 0, stream, emb, pts, lbl, ws);
  hipLaunchKernelGGL(kcenters, dim3(BB),  dim3(256), 0, stream, ws, acc);
  hipLaunchKernelGGL(kfused,   dim3(64 + 528 * BB), dim3(256), 0, stream,
                     lbl, (const ushort*)(ws + OFF_EMBH), pts, ws, acc);
  hipLaunchKernelGGL(kfinal,   dim3(1),   dim3(1),    0, stream, acc, out);
}